// Round 18
// baseline (626.060 us; speedup 1.0000x reference)
//
#include <hip/hip_runtime.h>

#define N_NODES 50000
#define N_EDGES 300000
#define G_GRAPHS 1024
#define HID 256
#define NLAYERS 4

typedef unsigned short ushort_t;
typedef __attribute__((ext_vector_type(8))) short bf16x8;
typedef __attribute__((ext_vector_type(8))) unsigned short u16x8;
typedef __attribute__((ext_vector_type(4))) float f32x4;

__device__ __forceinline__ float bf2f(ushort_t u) {
  unsigned int x = ((unsigned int)u) << 16;
  return __builtin_bit_cast(float, x);
}
__device__ __forceinline__ ushort_t f2bf(float f) {
  unsigned int x = __builtin_bit_cast(unsigned int, f);
  unsigned int lsb = (x >> 16) & 1u;
  x += 0x7fffu + lsb;
  return (ushort_t)(x >> 16);
}

// h(bf16) = relu(x @ encW + encB)
__global__ __launch_bounds__(256) void k_encoder(const float* __restrict__ x,
    const float* __restrict__ W, const float* __restrict__ b,
    ushort_t* __restrict__ h, int n)
{
  int j = threadIdx.x;
  float wcol[11];
#pragma unroll
  for (int k = 0; k < 11; ++k) wcol[k] = W[k * HID + j];
  float bj = b[j];
  __shared__ float xs[8][11];
  int base = blockIdx.x * 8;
  if (j < 88) {
    int r = j / 11, k = j % 11;
    int row = base + r;
    if (row < n) xs[r][k] = x[row * 11 + k];
  }
  __syncthreads();
#pragma unroll
  for (int r = 0; r < 8; ++r) {
    int row = base + r;
    if (row >= n) break;
    float acc = bj;
#pragma unroll
    for (int k = 0; k < 11; ++k) acc += xs[r][k] * wcol[k];
    h[(size_t)row * HID + j] = f2bf(fmaxf(acc, 0.f));
  }
}

// ---- CSR build ----
__global__ __launch_bounds__(256) void k_hist(const int* __restrict__ dst,
    int* __restrict__ offs, int E)
{
  int e = blockIdx.x * 256 + threadIdx.x;
  if (e < E) atomicAdd(&offs[dst[e]], 1);
}

// chunk-scan: exclusive scan within 1024-chunk, chunk totals to btot
__global__ __launch_bounds__(1024) void k_scanA(int* __restrict__ offs,
    int* __restrict__ btot, int n)
{
  __shared__ int wsum[16];
  int tid = threadIdx.x, lane = tid & 63, wid = tid >> 6;
  int idx = blockIdx.x * 1024 + tid;
  int v = (idx < n) ? offs[idx] : 0;
  int x = v;
#pragma unroll
  for (int off = 1; off < 64; off <<= 1) {
    int t = __shfl_up(x, off);
    if (lane >= off) x += t;
  }
  if (lane == 63) wsum[wid] = x;
  __syncthreads();
  if (wid == 0 && lane < 16) {
    int w = wsum[lane];
#pragma unroll
    for (int off = 1; off < 16; off <<= 1) {
      int t = __shfl_up(w, off);
      if (lane >= off) w += t;
    }
    wsum[lane] = w;
  }
  __syncthreads();
  int wbase = (wid == 0) ? 0 : wsum[wid - 1];
  if (idx < n) offs[idx] = wbase + x - v;
  if (tid == 0) btot[blockIdx.x] = wsum[15];
}

// add chunk base; each block computes its own base (49 serial L2-hot reads)
__global__ __launch_bounds__(1024) void k_scanC(int* __restrict__ offs,
    const int* __restrict__ btot, int n)
{
  __shared__ int sbase;
  if (threadIdx.x == 0) {
    int s = 0;
    for (int i = 0; i < blockIdx.x; ++i) s += btot[i];
    sbase = s;
  }
  __syncthreads();
  int idx = blockIdx.x * 1024 + threadIdx.x;
  if (idx < n) offs[idx] += sbase;
}

// fill CSR slots: esrc[p] = src, eab[p] = edge_attr packed to 8 bf16 (3 pad)
__global__ __launch_bounds__(256) void k_fill(const int* __restrict__ src,
    const int* __restrict__ dst, int* __restrict__ offs,
    int* __restrict__ esrc, ushort_t* __restrict__ eab,
    const float* __restrict__ ea, int E)
{
  int e = blockIdx.x * 256 + threadIdx.x;
  if (e < E) {
    int d = dst[e];
    int p = atomicAdd(&offs[d], 1);
    esrc[p] = src[e];
    const float* ep = ea + (size_t)e * 5;
    ushort4 lo = make_ushort4(f2bf(ep[0]), f2bf(ep[1]), f2bf(ep[2]), f2bf(ep[3]));
    ushort4 hi = make_ushort4(f2bf(ep[4]), 0, 0, 0);
    *(ushort4*)&eab[(size_t)p * 8] = lo;
    *(ushort4*)&eab[(size_t)p * 8 + 4] = hi;
  }
}

// W [256][256] f32 -> Wt [n][k] bf16 (transposed); handles W1 and W2 stacks
__global__ __launch_bounds__(256) void k_prep(const float* __restrict__ W1,
    const float* __restrict__ W2, ushort_t* __restrict__ Wt1,
    ushort_t* __restrict__ Wt2)
{
  __shared__ float ld[16][257];
  int mat = blockIdx.y & (NLAYERS - 1);
  int which = blockIdx.y >> 2;
  const float* Wm = (which ? W2 : W1) + (size_t)mat * HID * HID;
  ushort_t* Wtm = (which ? Wt2 : Wt1) + (size_t)mat * HID * HID;
  int k0 = blockIdx.x * 16;
  int tid = threadIdx.x;
#pragma unroll
  for (int i = 0; i < 16; ++i) ld[i][tid] = Wm[(size_t)(k0 + i) * HID + tid];
  __syncthreads();
#pragma unroll
  for (int v = 0; v < 4; ++v) {
    ushort4 u = make_ushort4(f2bf(ld[v*4+0][tid]), f2bf(ld[v*4+1][tid]),
                             f2bf(ld[v*4+2][tid]), f2bf(ld[v*4+3][tid]));
    *(ushort4*)&Wtm[(size_t)tid * HID + k0 + v * 4] = u;
  }
}

// generic W [K][N] f32 -> Wt [N][K] bf16
__global__ __launch_bounds__(256) void k_prept(const float* __restrict__ W,
    ushort_t* __restrict__ Wt, int K, int N)
{
  int idx = blockIdx.x * 256 + threadIdx.x;
  if (idx >= K * N) return;
  int n = idx / K, k = idx % K;
  Wt[idx] = f2bf(W[(size_t)k * N + n]);
}

struct ev5 { ushort_t s0, s1, s2, s3, s4; };

// per-edge MLP+accumulate (hygienic function, not macro)
__device__ __forceinline__ void edge_step(ev5 ev, ushort4 hv,
    const float4& w0, const float4& w1, const float4& w2, const float4& w3,
    const float4& w4, const float4& bi,
    float& ax, float& ay, float& az, float& aw)
{
  float v0 = bf2f(ev.s0), v1 = bf2f(ev.s1), v2 = bf2f(ev.s2),
        v3 = bf2f(ev.s3), v4 = bf2f(ev.s4);
  float m0 = bi.x, m1 = bi.y, m2 = bi.z, m3 = bi.w;
  m0 = fmaf(v0, w0.x, m0); m1 = fmaf(v0, w0.y, m1);
  m2 = fmaf(v0, w0.z, m2); m3 = fmaf(v0, w0.w, m3);
  m0 = fmaf(v1, w1.x, m0); m1 = fmaf(v1, w1.y, m1);
  m2 = fmaf(v1, w1.z, m2); m3 = fmaf(v1, w1.w, m3);
  m0 = fmaf(v2, w2.x, m0); m1 = fmaf(v2, w2.y, m1);
  m2 = fmaf(v2, w2.z, m2); m3 = fmaf(v2, w2.w, m3);
  m0 = fmaf(v3, w3.x, m0); m1 = fmaf(v3, w3.y, m1);
  m2 = fmaf(v3, w3.z, m2); m3 = fmaf(v3, w3.w, m3);
  m0 = fmaf(v4, w4.x, m0); m1 = fmaf(v4, w4.y, m1);
  m2 = fmaf(v4, w4.z, m2); m3 = fmaf(v4, w4.w, m3);
  m0 += bf2f(hv.x); m1 += bf2f(hv.y); m2 += bf2f(hv.z); m3 += bf2f(hv.w);
  ax += fmaxf(m0, 0.f); ay += fmaxf(m1, 0.f);
  az += fmaxf(m2, 0.f); aw += fmaxf(m3, 0.f);
}

// 2 waves per node (even/odd edge split, full rows): halves the serial
// per-wave edge chain and doubles wave count for latency hiding. Partials
// merged via LDS with a single tail barrier. Block = 4 waves = 2 nodes.
// zin[i] = h[i] + sum relu(h[src] + ea@eW + eb). Block 0 zeroes stats.
__global__ __launch_bounds__(256) void k_gather(const ushort_t* __restrict__ h,
    const int* __restrict__ offs, const int* __restrict__ esrc,
    const ushort_t* __restrict__ eab, const float* __restrict__ eW,
    const float* __restrict__ eb, ushort_t* __restrict__ zin,
    float* __restrict__ stats, int n)
{
  __shared__ float part[2][HID];
  int tid = threadIdx.x;
  if (blockIdx.x == 0) { stats[tid] = 0.f; stats[HID + tid] = 0.f; }
  int wave = tid >> 6, lane = tid & 63;
  int nloc = wave >> 1;        // node within block (0..1)
  int half = wave & 1;         // even/odd edge stream
  int node = blockIdx.x * 2 + nloc;   // N_NODES even -> always < n
  int c4 = lane * 4;
  float4 w0 = *(const float4*)&eW[0 * HID + c4];
  float4 w1 = *(const float4*)&eW[1 * HID + c4];
  float4 w2 = *(const float4*)&eW[2 * HID + c4];
  float4 w3 = *(const float4*)&eW[3 * HID + c4];
  float4 w4 = *(const float4*)&eW[4 * HID + c4];
  float4 bi = *(const float4*)&eb[c4];
  int lo = (node == 0) ? 0 : offs[node - 1];
  int hi = offs[node];
  float ax = 0.f, ay = 0.f, az = 0.f, aw = 0.f;
  int p = lo + half;
  // depth-2 pipeline over this wave's stride-2 edge stream
  for (; p + 2 < hi; p += 4) {
    int s0 = esrc[p], s1 = esrc[p + 2];
    ev5 ea0 = *(const ev5*)&eab[(size_t)p * 8];
    ev5 ea1 = *(const ev5*)&eab[(size_t)(p + 2) * 8];
    ushort4 h0 = *(const ushort4*)&h[(size_t)s0 * HID + c4];
    ushort4 h1 = *(const ushort4*)&h[(size_t)s1 * HID + c4];
    edge_step(ea0, h0, w0, w1, w2, w3, w4, bi, ax, ay, az, aw);
    edge_step(ea1, h1, w0, w1, w2, w3, w4, bi, ax, ay, az, aw);
  }
  if (p < hi) {
    int s0 = esrc[p];
    ev5 ea0 = *(const ev5*)&eab[(size_t)p * 8];
    ushort4 h0 = *(const ushort4*)&h[(size_t)s0 * HID + c4];
    edge_step(ea0, h0, w0, w1, w2, w3, w4, bi, ax, ay, az, aw);
  }
  if (half == 1) {
    *(float4*)&part[nloc][c4] = make_float4(ax, ay, az, aw);
  }
  __syncthreads();
  if (half == 0) {
    float4 pv = *(const float4*)&part[nloc][c4];
    ushort4 ho = *(const ushort4*)&h[(size_t)node * HID + c4];
    ax += pv.x + bf2f(ho.x); ay += pv.y + bf2f(ho.y);
    az += pv.z + bf2f(ho.z); aw += pv.w + bf2f(ho.w);
    *(ushort4*)&zin[(size_t)node * HID + c4] =
        make_ushort4(f2bf(ax), f2bf(ay), f2bf(az), f2bf(aw));
  }
}

// Fused layer MLP: z2 = relu(zin@W1+b1)@W2 + b2, fused column stats.
// W1-frags in registers, W2 in LDS (staged once). A-prefetch for the NEXT
// tile is issued at the TOP of the iteration so stage-1 MFMAs + LDS writes
// cover its latency before the barrier's vmcnt(0) drain (the drain was the
// per-iteration stall: 1 block/CU, all waves barrier-coupled).
__global__ __launch_bounds__(512, 1) void k_mlp(const ushort_t* __restrict__ A,
    const ushort_t* __restrict__ Wt1, const float* __restrict__ b1,
    const ushort_t* __restrict__ Wt2, const float* __restrict__ b2,
    ushort_t* __restrict__ out, float* __restrict__ stats, int M)
{
  __shared__ alignas(16) ushort_t w2L[65536];
  __shared__ alignas(16) ushort_t z1s[2][16 * 264];
  int tid = threadIdx.x;
  int wave = tid >> 6, lane = tid & 63;
  int m = lane & 15, quad = lane >> 4;
  int col0 = wave * 32;
  for (int c = tid; c < 8192; c += 512) {
    int f = c >> 6, l = c & 63;
    int ctg = f >> 3, kt = f & 7;
    int n = ctg * 16 + (l & 15);
    int k = kt * 32 + (l >> 4) * 8;
    *(u16x8*)&w2L[f * 512 + l * 8] = *(const u16x8*)(Wt2 + (size_t)n * HID + k);
  }
  bf16x8 w1f[2][8];
#pragma unroll
  for (int ct = 0; ct < 2; ++ct)
#pragma unroll
    for (int kt = 0; kt < 8; ++kt)
      w1f[ct][kt] = *(const bf16x8*)(
          Wt1 + (size_t)(col0 + ct * 16 + m) * HID + kt * 32 + quad * 8);
  float bv1[2] = {b1[col0 + m], b1[col0 + 16 + m]};
  float bv2[2] = {b2[col0 + m], b2[col0 + 16 + m]};
  float csum[2] = {0.f, 0.f}, csq[2] = {0.f, 0.f};
  int ntiles = M >> 4;
  int parity = 0;
  int ctg0 = wave * 2, ctg1 = wave * 2 + 1;
  __syncthreads();
  int t = blockIdx.x;
  bf16x8 af[8];
  if (t < ntiles) {
    const ushort_t* Ap = A + (size_t)(t * 16 + m) * HID + quad * 8;
#pragma unroll
    for (int kt = 0; kt < 8; ++kt) af[kt] = *(const bf16x8*)(Ap + kt * 32);
  }
  for (; t < ntiles; t += gridDim.x) {
    // prefetch NEXT tile first: stage-1 compute below covers its latency
    int tn = t + gridDim.x;
    int tcl = (tn < ntiles) ? tn : t;
    const ushort_t* Apn = A + (size_t)(tcl * 16 + m) * HID + quad * 8;
    bf16x8 afn[8];
#pragma unroll
    for (int kt = 0; kt < 8; ++kt) afn[kt] = *(const bf16x8*)(Apn + kt * 32);
    // stage 1: z1 = relu(zin_tile @ W1 + b1)
    f32x4 a0 = (f32x4){0.f, 0.f, 0.f, 0.f};
    f32x4 a1 = (f32x4){0.f, 0.f, 0.f, 0.f};
#pragma unroll
    for (int kt = 0; kt < 8; ++kt) {
      a0 = __builtin_amdgcn_mfma_f32_16x16x32_bf16(af[kt], w1f[0][kt], a0, 0, 0, 0);
      a1 = __builtin_amdgcn_mfma_f32_16x16x32_bf16(af[kt], w1f[1][kt], a1, 0, 0, 0);
    }
    ushort_t* buf = z1s[parity];
#pragma unroll
    for (int reg = 0; reg < 4; ++reg) {
      int r = quad * 4 + reg;
      buf[r * 264 + col0 + m]      = f2bf(fmaxf(a0[reg] + bv1[0], 0.f));
      buf[r * 264 + col0 + 16 + m] = f2bf(fmaxf(a1[reg] + bv1[1], 0.f));
    }
    __syncthreads();
    // stage 2: z2 = z1_tile @ W2 + b2, W2 from LDS
    f32x4 c0 = (f32x4){0.f, 0.f, 0.f, 0.f};
    f32x4 c1 = (f32x4){0.f, 0.f, 0.f, 0.f};
#pragma unroll
    for (int kt = 0; kt < 8; ++kt) {
      bf16x8 zf = *(const bf16x8*)&buf[m * 264 + kt * 32 + quad * 8];
      bf16x8 b0 = *(const bf16x8*)&w2L[(ctg0 * 8 + kt) * 512 + lane * 8];
      bf16x8 b1r = *(const bf16x8*)&w2L[(ctg1 * 8 + kt) * 512 + lane * 8];
      c0 = __builtin_amdgcn_mfma_f32_16x16x32_bf16(zf, b0, c0, 0, 0, 0);
      c1 = __builtin_amdgcn_mfma_f32_16x16x32_bf16(zf, b1r, c1, 0, 0, 0);
    }
    int rb = t * 16 + quad * 4;
#pragma unroll
    for (int reg = 0; reg < 4; ++reg) {
      float o0 = c0[reg] + bv2[0];
      float o1 = c1[reg] + bv2[1];
      out[(size_t)(rb + reg) * HID + col0 + m] = f2bf(o0);
      out[(size_t)(rb + reg) * HID + col0 + 16 + m] = f2bf(o1);
      csum[0] += o0; csq[0] = fmaf(o0, o0, csq[0]);
      csum[1] += o1; csq[1] = fmaf(o1, o1, csq[1]);
    }
#pragma unroll
    for (int kt = 0; kt < 8; ++kt) af[kt] = afn[kt];
    parity ^= 1;
  }
#pragma unroll
  for (int ct = 0; ct < 2; ++ct) {
    float s = csum[ct], q = csq[ct];
    s += __shfl_xor(s, 16); s += __shfl_xor(s, 32);
    q += __shfl_xor(q, 16); q += __shfl_xor(q, 32);
    if (quad == 0) {
      unsafeAtomicAdd(&stats[col0 + ct * 16 + m], s);
      unsafeAtomicAdd(&stats[HID + col0 + ct * 16 + m], q);
    }
  }
}

// h(bf16) = relu(z*scale + shift) + h ; scale/shift computed from raw stats
__global__ __launch_bounds__(256) void k_bn_apply(const ushort_t* __restrict__ z,
    const float* __restrict__ stats, const float* __restrict__ g,
    const float* __restrict__ b, ushort_t* __restrict__ h, int total4)
{
  int idx = blockIdx.x * 256 + threadIdx.x;
  if (idx >= total4) return;
  int col = (idx & 63) * 4;
  const float inv_n = 1.f / (float)N_NODES;
  float sc[4], sh[4];
#pragma unroll
  for (int c = 0; c < 4; ++c) {
    float mu = stats[col + c] * inv_n;
    float var = stats[HID + col + c] * inv_n - mu * mu;
    float rs = rsqrtf(var + 1e-5f);
    sc[c] = g[col + c] * rs;
    sh[c] = b[col + c] - mu * sc[c];
  }
  ushort4 zv = *(const ushort4*)(z + (size_t)idx * 4);
  ushort4 hv = *(const ushort4*)(h + (size_t)idx * 4);
  float o0 = fmaxf(fmaf(bf2f(zv.x), sc[0], sh[0]), 0.f) + bf2f(hv.x);
  float o1 = fmaxf(fmaf(bf2f(zv.y), sc[1], sh[1]), 0.f) + bf2f(hv.y);
  float o2 = fmaxf(fmaf(bf2f(zv.z), sc[2], sh[2]), 0.f) + bf2f(hv.z);
  float o3 = fmaxf(fmaf(bf2f(zv.w), sc[3], sh[3]), 0.f) + bf2f(hv.w);
  *(ushort4*)(h + (size_t)idx * 4) = make_ushort4(f2bf(o0), f2bf(o1), f2bf(o2), f2bf(o3));
}

__device__ __forceinline__ int lbound(const int* __restrict__ b, int n, int key) {
  int lo = 0, hi = n;
  while (lo < hi) {
    int mid = (lo + hi) >> 1;
    if (b[mid] < key) lo = mid + 1; else hi = mid;
  }
  return lo;
}

// pool per graph (batch sorted): gf[g] = [mean | sum | max] as bf16
__global__ __launch_bounds__(256) void k_pool(const ushort_t* __restrict__ h,
    const int* __restrict__ batch, ushort_t* __restrict__ gf)
{
  int g = blockIdx.x, j = threadIdx.x;
  int lo = lbound(batch, N_NODES, g);
  int hi = lbound(batch, N_NODES, g + 1);
  float s = 0.f, mx = 0.f;  // h >= 0 by construction
  int i = lo;
  for (; i + 1 < hi; i += 2) {
    float v0 = bf2f(h[(size_t)i * HID + j]);
    float v1 = bf2f(h[(size_t)(i + 1) * HID + j]);
    s += v0 + v1; mx = fmaxf(mx, fmaxf(v0, v1));
  }
  if (i < hi) {
    float v = bf2f(h[(size_t)i * HID + j]);
    s += v; mx = fmaxf(mx, v);
  }
  float cntv = fmaxf((float)(hi - lo), 1.f);
  size_t base = (size_t)g * 768;
  gf[base + j] = f2bf(s / cntv);
  gf[base + 256 + j] = f2bf(s);
  gf[base + 512 + j] = f2bf(mx);
}

// small B-in-registers MFMA GEMM for the head: out[M,N] = A[M,K] @ Bt^T + bias
template<int KT, int DO_RELU>
__global__ __launch_bounds__(256, 1) void k_head_gemm(const ushort_t* __restrict__ A,
    const ushort_t* __restrict__ Bt, const float* __restrict__ bias,
    ushort_t* __restrict__ out, int M, int N)
{
  const int K = KT * 32;
  int tid = threadIdx.x;
  int wave = tid >> 6, lane = tid & 63;
  int m = lane & 15, quad = lane >> 4;
  int col = (blockIdx.y * 4 + wave) * 16 + m;
  bf16x8 bfrag[KT];
#pragma unroll
  for (int kt = 0; kt < KT; ++kt)
    bfrag[kt] = *(const bf16x8*)(Bt + (size_t)col * K + kt * 32 + quad * 8);
  float bv = bias[col];
  int ntiles = M >> 4;
  for (int t = blockIdx.x; t < ntiles; t += gridDim.x) {
    const ushort_t* Ap = A + (size_t)(t * 16 + m) * K + quad * 8;
    bf16x8 af[KT];
#pragma unroll
    for (int kt = 0; kt < KT; ++kt) af[kt] = *(const bf16x8*)(Ap + kt * 32);
    f32x4 acc = (f32x4){0.f, 0.f, 0.f, 0.f};
#pragma unroll
    for (int kt = 0; kt < KT; ++kt)
      acc = __builtin_amdgcn_mfma_f32_16x16x32_bf16(af[kt], bfrag[kt], acc, 0, 0, 0);
    int rb = t * 16 + quad * 4;
#pragma unroll
    for (int reg = 0; reg < 4; ++reg) {
      float o = acc[reg] + bv;
      if (DO_RELU) o = fmaxf(o, 0.f);
      out[(size_t)(rb + reg) * N + col] = f2bf(o);
    }
  }
}

// out[g] = dot(g2[g], W3) + b3; one wave per graph
__global__ __launch_bounds__(256) void k_head_out(const ushort_t* __restrict__ g2,
    const float* __restrict__ W3, const float* __restrict__ b3,
    float* __restrict__ out)
{
  int wave = threadIdx.x >> 6, lane = threadIdx.x & 63;
  int g = blockIdx.x * 4 + wave;
  ushort2 v = *(const ushort2*)&g2[(size_t)g * 128 + lane * 2];
  float p = bf2f(v.x) * W3[lane * 2] + bf2f(v.y) * W3[lane * 2 + 1];
#pragma unroll
  for (int off = 32; off > 0; off >>= 1) p += __shfl_down(p, off);
  if (lane == 0) out[g] = p + b3[0];
}

extern "C" void kernel_launch(void* const* d_in, const int* in_sizes, int n_in,
                              void* d_out, int out_size, void* d_ws, size_t ws_size,
                              hipStream_t stream)
{
  const float* x     = (const float*)d_in[0];
  const int*   ei    = (const int*)d_in[1];
  const float* ea    = (const float*)d_in[2];
  const int*   batch = (const int*)d_in[3];
  const float* encW  = (const float*)d_in[4];
  const float* encB  = (const float*)d_in[5];
  const float* edgeW = (const float*)d_in[6];
  const float* edgeB = (const float*)d_in[7];
  const float* W1    = (const float*)d_in[8];
  const float* b1    = (const float*)d_in[9];
  const float* W2    = (const float*)d_in[10];
  const float* b2    = (const float*)d_in[11];
  const float* bng   = (const float*)d_in[12];
  const float* bnb   = (const float*)d_in[13];
  const float* hW1   = (const float*)d_in[14];
  const float* hb1   = (const float*)d_in[15];
  const float* hW2   = (const float*)d_in[16];
  const float* hb2   = (const float*)d_in[17];
  const float* hW3   = (const float*)d_in[18];
  const float* hb3   = (const float*)d_in[19];
  float* out = (float*)d_out;

  const size_t NH = (size_t)N_NODES * HID;
  char* base = (char*)d_ws;
  auto alloc = [&](size_t bytes) -> char* {
    char* p = base; base += (bytes + 63) & ~(size_t)63; return p;
  };
  float*    stats = (float*)alloc(512 * 4);
  int*      offs  = (int*)alloc(50001 * 4);
  int*      btot  = (int*)alloc(64 * 4);
  int*      esrc  = (int*)alloc((size_t)N_EDGES * 4);
  ushort_t* eab   = (ushort_t*)alloc((size_t)N_EDGES * 8 * 2);
  ushort_t* Wt1   = (ushort_t*)alloc((size_t)NLAYERS * HID * HID * 2);
  ushort_t* Wt2   = (ushort_t*)alloc((size_t)NLAYERS * HID * HID * 2);
  ushort_t* hW1t  = (ushort_t*)alloc((size_t)768 * 256 * 2);
  ushort_t* hW2t  = (ushort_t*)alloc((size_t)256 * 128 * 2);
  ushort_t* gf    = (ushort_t*)alloc((size_t)G_GRAPHS * 768 * 2);
  ushort_t* g1    = (ushort_t*)alloc((size_t)G_GRAPHS * 256 * 2);
  ushort_t* g2    = (ushort_t*)alloc((size_t)G_GRAPHS * 128 * 2);
  ushort_t* zin   = (ushort_t*)alloc(NH * 2);  // also reused as z2
  ushort_t* h     = (ushort_t*)alloc(NH * 2);
  // total ~84 MB

  const int* src = ei;
  const int* dst = ei + N_EDGES;

  // setup: CSR build + weight prep (once per call)
  hipMemsetAsync(offs, 0, 50001 * sizeof(int), stream);
  k_hist<<<(N_EDGES + 255) / 256, 256, 0, stream>>>(dst, offs, N_EDGES);
  const int NSB = (N_NODES + 1023) / 1024;  // 49
  k_scanA<<<NSB, 1024, 0, stream>>>(offs, btot, N_NODES);
  k_scanC<<<NSB, 1024, 0, stream>>>(offs, btot, N_NODES);
  k_fill<<<(N_EDGES + 255) / 256, 256, 0, stream>>>(src, dst, offs, esrc, eab, ea, N_EDGES);
  k_prep<<<dim3(16, 2 * NLAYERS), 256, 0, stream>>>(W1, W2, Wt1, Wt2);
  k_prept<<<(768 * 256 + 255) / 256, 256, 0, stream>>>(hW1, hW1t, 768, 256);
  k_prept<<<(256 * 128 + 255) / 256, 256, 0, stream>>>(hW2, hW2t, 256, 128);

  k_encoder<<<(N_NODES + 7) / 8, 256, 0, stream>>>(x, encW, encB, h, N_NODES);

  for (int l = 0; l < NLAYERS; ++l) {
    k_gather<<<N_NODES / 2, 256, 0, stream>>>(
        h, offs, esrc, eab, edgeW + (size_t)l * 5 * HID, edgeB + (size_t)l * HID,
        zin, stats, N_NODES);
    // z2 = relu(zin@W1+b1)@W2 + b2 (in place zin -> zin), fused stats
    k_mlp<<<256, 512, 0, stream>>>(
        zin, Wt1 + (size_t)l * HID * HID, b1 + (size_t)l * HID,
        Wt2 + (size_t)l * HID * HID, b2 + (size_t)l * HID, zin, stats, N_NODES);
    k_bn_apply<<<(N_NODES * HID / 4 + 255) / 256, 256, 0, stream>>>(
        zin, stats, bng + (size_t)l * HID, bnb + (size_t)l * HID, h, N_NODES * HID / 4);
  }

  k_pool<<<G_GRAPHS, 256, 0, stream>>>(h, batch, gf);
  k_head_gemm<24, 1><<<dim3(16, 4), 256, 0, stream>>>(gf, hW1t, hb1, g1, G_GRAPHS, 256);
  k_head_gemm<8, 1><<<dim3(16, 2), 256, 0, stream>>>(g1, hW2t, hb2, g2, G_GRAPHS, 128);
  k_head_out<<<G_GRAPHS / 4, 256, 0, stream>>>(g2, hW3, hb3, out);
}

// Round 19
// 609.373 us; speedup vs baseline: 1.0274x; 1.0274x over previous
//
#include <hip/hip_runtime.h>

#define N_NODES 50000
#define N_EDGES 300000
#define G_GRAPHS 1024
#define HID 256
#define NLAYERS 4

typedef unsigned short ushort_t;
typedef __attribute__((ext_vector_type(8))) short bf16x8;
typedef __attribute__((ext_vector_type(8))) unsigned short u16x8;
typedef __attribute__((ext_vector_type(4))) float f32x4;

__device__ __forceinline__ float bf2f(ushort_t u) {
  unsigned int x = ((unsigned int)u) << 16;
  return __builtin_bit_cast(float, x);
}
__device__ __forceinline__ ushort_t f2bf(float f) {
  unsigned int x = __builtin_bit_cast(unsigned int, f);
  unsigned int lsb = (x >> 16) & 1u;
  x += 0x7fffu + lsb;
  return (ushort_t)(x >> 16);
}

// h(bf16) = relu(x @ encW + encB)
__global__ __launch_bounds__(256) void k_encoder(const float* __restrict__ x,
    const float* __restrict__ W, const float* __restrict__ b,
    ushort_t* __restrict__ h, int n)
{
  int j = threadIdx.x;
  float wcol[11];
#pragma unroll
  for (int k = 0; k < 11; ++k) wcol[k] = W[k * HID + j];
  float bj = b[j];
  __shared__ float xs[8][11];
  int base = blockIdx.x * 8;
  if (j < 88) {
    int r = j / 11, k = j % 11;
    int row = base + r;
    if (row < n) xs[r][k] = x[row * 11 + k];
  }
  __syncthreads();
#pragma unroll
  for (int r = 0; r < 8; ++r) {
    int row = base + r;
    if (row >= n) break;
    float acc = bj;
#pragma unroll
    for (int k = 0; k < 11; ++k) acc += xs[r][k] * wcol[k];
    h[(size_t)row * HID + j] = f2bf(fmaxf(acc, 0.f));
  }
}

// ---- CSR build ----
__global__ __launch_bounds__(256) void k_hist(const int* __restrict__ dst,
    int* __restrict__ offs, int E)
{
  int e = blockIdx.x * 256 + threadIdx.x;
  if (e < E) atomicAdd(&offs[dst[e]], 1);
}

// chunk-scan: exclusive scan within 1024-chunk, chunk totals to btot
__global__ __launch_bounds__(1024) void k_scanA(int* __restrict__ offs,
    int* __restrict__ btot, int n)
{
  __shared__ int wsum[16];
  int tid = threadIdx.x, lane = tid & 63, wid = tid >> 6;
  int idx = blockIdx.x * 1024 + tid;
  int v = (idx < n) ? offs[idx] : 0;
  int x = v;
#pragma unroll
  for (int off = 1; off < 64; off <<= 1) {
    int t = __shfl_up(x, off);
    if (lane >= off) x += t;
  }
  if (lane == 63) wsum[wid] = x;
  __syncthreads();
  if (wid == 0 && lane < 16) {
    int w = wsum[lane];
#pragma unroll
    for (int off = 1; off < 16; off <<= 1) {
      int t = __shfl_up(w, off);
      if (lane >= off) w += t;
    }
    wsum[lane] = w;
  }
  __syncthreads();
  int wbase = (wid == 0) ? 0 : wsum[wid - 1];
  if (idx < n) offs[idx] = wbase + x - v;
  if (tid == 0) btot[blockIdx.x] = wsum[15];
}

// add chunk base; each block computes its own base (49 serial L2-hot reads)
__global__ __launch_bounds__(1024) void k_scanC(int* __restrict__ offs,
    const int* __restrict__ btot, int n)
{
  __shared__ int sbase;
  if (threadIdx.x == 0) {
    int s = 0;
    for (int i = 0; i < blockIdx.x; ++i) s += btot[i];
    sbase = s;
  }
  __syncthreads();
  int idx = blockIdx.x * 1024 + threadIdx.x;
  if (idx < n) offs[idx] += sbase;
}

// fill CSR slots: esrc[p] = src, eab[p] = edge_attr packed to 8 bf16 (3 pad)
__global__ __launch_bounds__(256) void k_fill(const int* __restrict__ src,
    const int* __restrict__ dst, int* __restrict__ offs,
    int* __restrict__ esrc, ushort_t* __restrict__ eab,
    const float* __restrict__ ea, int E)
{
  int e = blockIdx.x * 256 + threadIdx.x;
  if (e < E) {
    int d = dst[e];
    int p = atomicAdd(&offs[d], 1);
    esrc[p] = src[e];
    const float* ep = ea + (size_t)e * 5;
    ushort4 lo = make_ushort4(f2bf(ep[0]), f2bf(ep[1]), f2bf(ep[2]), f2bf(ep[3]));
    ushort4 hi = make_ushort4(f2bf(ep[4]), 0, 0, 0);
    *(ushort4*)&eab[(size_t)p * 8] = lo;
    *(ushort4*)&eab[(size_t)p * 8 + 4] = hi;
  }
}

// W [256][256] f32 -> Wt [n][k] bf16 (transposed); handles W1 and W2 stacks
__global__ __launch_bounds__(256) void k_prep(const float* __restrict__ W1,
    const float* __restrict__ W2, ushort_t* __restrict__ Wt1,
    ushort_t* __restrict__ Wt2)
{
  __shared__ float ld[16][257];
  int mat = blockIdx.y & (NLAYERS - 1);
  int which = blockIdx.y >> 2;
  const float* Wm = (which ? W2 : W1) + (size_t)mat * HID * HID;
  ushort_t* Wtm = (which ? Wt2 : Wt1) + (size_t)mat * HID * HID;
  int k0 = blockIdx.x * 16;
  int tid = threadIdx.x;
#pragma unroll
  for (int i = 0; i < 16; ++i) ld[i][tid] = Wm[(size_t)(k0 + i) * HID + tid];
  __syncthreads();
#pragma unroll
  for (int v = 0; v < 4; ++v) {
    ushort4 u = make_ushort4(f2bf(ld[v*4+0][tid]), f2bf(ld[v*4+1][tid]),
                             f2bf(ld[v*4+2][tid]), f2bf(ld[v*4+3][tid]));
    *(ushort4*)&Wtm[(size_t)tid * HID + k0 + v * 4] = u;
  }
}

// generic W [K][N] f32 -> Wt [N][K] bf16
__global__ __launch_bounds__(256) void k_prept(const float* __restrict__ W,
    ushort_t* __restrict__ Wt, int K, int N)
{
  int idx = blockIdx.x * 256 + threadIdx.x;
  if (idx >= K * N) return;
  int n = idx / K, k = idx % K;
  Wt[idx] = f2bf(W[(size_t)k * N + n]);
}

struct ev5 { ushort_t s0, s1, s2, s3, s4; };

// per-edge MLP+accumulate (hygienic function, not macro)
__device__ __forceinline__ void edge_step(ev5 ev, ushort4 hv,
    const float4& w0, const float4& w1, const float4& w2, const float4& w3,
    const float4& w4, const float4& bi,
    float& ax, float& ay, float& az, float& aw)
{
  float v0 = bf2f(ev.s0), v1 = bf2f(ev.s1), v2 = bf2f(ev.s2),
        v3 = bf2f(ev.s3), v4 = bf2f(ev.s4);
  float m0 = bi.x, m1 = bi.y, m2 = bi.z, m3 = bi.w;
  m0 = fmaf(v0, w0.x, m0); m1 = fmaf(v0, w0.y, m1);
  m2 = fmaf(v0, w0.z, m2); m3 = fmaf(v0, w0.w, m3);
  m0 = fmaf(v1, w1.x, m0); m1 = fmaf(v1, w1.y, m1);
  m2 = fmaf(v1, w1.z, m2); m3 = fmaf(v1, w1.w, m3);
  m0 = fmaf(v2, w2.x, m0); m1 = fmaf(v2, w2.y, m1);
  m2 = fmaf(v2, w2.z, m2); m3 = fmaf(v2, w2.w, m3);
  m0 = fmaf(v3, w3.x, m0); m1 = fmaf(v3, w3.y, m1);
  m2 = fmaf(v3, w3.z, m2); m3 = fmaf(v3, w3.w, m3);
  m0 = fmaf(v4, w4.x, m0); m1 = fmaf(v4, w4.y, m1);
  m2 = fmaf(v4, w4.z, m2); m3 = fmaf(v4, w4.w, m3);
  m0 += bf2f(hv.x); m1 += bf2f(hv.y); m2 += bf2f(hv.z); m3 += bf2f(hv.w);
  ax += fmaxf(m0, 0.f); ay += fmaxf(m1, 0.f);
  az += fmaxf(m2, 0.f); aw += fmaxf(m3, 0.f);
}

// one wave per node, 4-edge software pipeline; CSR-ordered esrc/eab streams.
// (round-16 version — measured 48.4 us; the round-18 stride-2 split
// regressed to 55 us by breaking stream coalescing.)
// zin[i] = h[i] + sum relu(h[src] + ea@eW + eb). Block 0 zeroes stats.
__global__ __launch_bounds__(256) void k_gather(const ushort_t* __restrict__ h,
    const int* __restrict__ offs, const int* __restrict__ esrc,
    const ushort_t* __restrict__ eab, const float* __restrict__ eW,
    const float* __restrict__ eb, ushort_t* __restrict__ zin,
    float* __restrict__ stats, int n)
{
  int tid = threadIdx.x;
  if (blockIdx.x == 0) { stats[tid] = 0.f; stats[HID + tid] = 0.f; }
  int wave = tid >> 6, lane = tid & 63;
  int node = blockIdx.x * 4 + wave;
  int c4 = lane * 4;
  float4 w0 = *(const float4*)&eW[0 * HID + c4];
  float4 w1 = *(const float4*)&eW[1 * HID + c4];
  float4 w2 = *(const float4*)&eW[2 * HID + c4];
  float4 w3 = *(const float4*)&eW[3 * HID + c4];
  float4 w4 = *(const float4*)&eW[4 * HID + c4];
  float4 bi = *(const float4*)&eb[c4];
  if (node >= n) return;
  int lo = (node == 0) ? 0 : offs[node - 1];
  int hi = offs[node];
  ushort4 ho = *(const ushort4*)&h[(size_t)node * HID + c4];
  float ax = bf2f(ho.x), ay = bf2f(ho.y), az = bf2f(ho.z), aw = bf2f(ho.w);
  int p = lo;
  for (; p + 3 < hi; p += 4) {
    int s0 = esrc[p], s1 = esrc[p + 1], s2 = esrc[p + 2], s3 = esrc[p + 3];
    ev5 ea0 = *(const ev5*)&eab[(size_t)(p + 0) * 8];
    ev5 ea1 = *(const ev5*)&eab[(size_t)(p + 1) * 8];
    ev5 ea2 = *(const ev5*)&eab[(size_t)(p + 2) * 8];
    ev5 ea3 = *(const ev5*)&eab[(size_t)(p + 3) * 8];
    ushort4 h0 = *(const ushort4*)&h[(size_t)s0 * HID + c4];
    ushort4 h1 = *(const ushort4*)&h[(size_t)s1 * HID + c4];
    ushort4 h2 = *(const ushort4*)&h[(size_t)s2 * HID + c4];
    ushort4 h3 = *(const ushort4*)&h[(size_t)s3 * HID + c4];
    edge_step(ea0, h0, w0, w1, w2, w3, w4, bi, ax, ay, az, aw);
    edge_step(ea1, h1, w0, w1, w2, w3, w4, bi, ax, ay, az, aw);
    edge_step(ea2, h2, w0, w1, w2, w3, w4, bi, ax, ay, az, aw);
    edge_step(ea3, h3, w0, w1, w2, w3, w4, bi, ax, ay, az, aw);
  }
  for (; p < hi; ++p) {
    int s0 = esrc[p];
    ev5 ea0 = *(const ev5*)&eab[(size_t)p * 8];
    ushort4 h0 = *(const ushort4*)&h[(size_t)s0 * HID + c4];
    edge_step(ea0, h0, w0, w1, w2, w3, w4, bi, ax, ay, az, aw);
  }
  *(ushort4*)&zin[(size_t)node * HID + c4] =
      make_ushort4(f2bf(ax), f2bf(ay), f2bf(az), f2bf(aw));
}

// Fused layer MLP: z2 = relu(zin@W1+b1)@W2 + b2, fused column stats.
// W1-frags in registers, W2 in LDS (staged once). A-prefetch at top of
// iteration so stage-1 MFMAs cover its latency before the barrier drain.
__global__ __launch_bounds__(512, 1) void k_mlp(const ushort_t* __restrict__ A,
    const ushort_t* __restrict__ Wt1, const float* __restrict__ b1,
    const ushort_t* __restrict__ Wt2, const float* __restrict__ b2,
    ushort_t* __restrict__ out, float* __restrict__ stats, int M)
{
  __shared__ alignas(16) ushort_t w2L[65536];
  __shared__ alignas(16) ushort_t z1s[2][16 * 264];
  int tid = threadIdx.x;
  int wave = tid >> 6, lane = tid & 63;
  int m = lane & 15, quad = lane >> 4;
  int col0 = wave * 32;
  for (int c = tid; c < 8192; c += 512) {
    int f = c >> 6, l = c & 63;
    int ctg = f >> 3, kt = f & 7;
    int n = ctg * 16 + (l & 15);
    int k = kt * 32 + (l >> 4) * 8;
    *(u16x8*)&w2L[f * 512 + l * 8] = *(const u16x8*)(Wt2 + (size_t)n * HID + k);
  }
  bf16x8 w1f[2][8];
#pragma unroll
  for (int ct = 0; ct < 2; ++ct)
#pragma unroll
    for (int kt = 0; kt < 8; ++kt)
      w1f[ct][kt] = *(const bf16x8*)(
          Wt1 + (size_t)(col0 + ct * 16 + m) * HID + kt * 32 + quad * 8);
  float bv1[2] = {b1[col0 + m], b1[col0 + 16 + m]};
  float bv2[2] = {b2[col0 + m], b2[col0 + 16 + m]};
  float csum[2] = {0.f, 0.f}, csq[2] = {0.f, 0.f};
  int ntiles = M >> 4;
  int parity = 0;
  int ctg0 = wave * 2, ctg1 = wave * 2 + 1;
  __syncthreads();
  int t = blockIdx.x;
  bf16x8 af[8];
  if (t < ntiles) {
    const ushort_t* Ap = A + (size_t)(t * 16 + m) * HID + quad * 8;
#pragma unroll
    for (int kt = 0; kt < 8; ++kt) af[kt] = *(const bf16x8*)(Ap + kt * 32);
  }
  for (; t < ntiles; t += gridDim.x) {
    int tn = t + gridDim.x;
    int tcl = (tn < ntiles) ? tn : t;
    const ushort_t* Apn = A + (size_t)(tcl * 16 + m) * HID + quad * 8;
    bf16x8 afn[8];
#pragma unroll
    for (int kt = 0; kt < 8; ++kt) afn[kt] = *(const bf16x8*)(Apn + kt * 32);
    f32x4 a0 = (f32x4){0.f, 0.f, 0.f, 0.f};
    f32x4 a1 = (f32x4){0.f, 0.f, 0.f, 0.f};
#pragma unroll
    for (int kt = 0; kt < 8; ++kt) {
      a0 = __builtin_amdgcn_mfma_f32_16x16x32_bf16(af[kt], w1f[0][kt], a0, 0, 0, 0);
      a1 = __builtin_amdgcn_mfma_f32_16x16x32_bf16(af[kt], w1f[1][kt], a1, 0, 0, 0);
    }
    ushort_t* buf = z1s[parity];
#pragma unroll
    for (int reg = 0; reg < 4; ++reg) {
      int r = quad * 4 + reg;
      buf[r * 264 + col0 + m]      = f2bf(fmaxf(a0[reg] + bv1[0], 0.f));
      buf[r * 264 + col0 + 16 + m] = f2bf(fmaxf(a1[reg] + bv1[1], 0.f));
    }
    __syncthreads();
    f32x4 c0 = (f32x4){0.f, 0.f, 0.f, 0.f};
    f32x4 c1 = (f32x4){0.f, 0.f, 0.f, 0.f};
#pragma unroll
    for (int kt = 0; kt < 8; ++kt) {
      bf16x8 zf = *(const bf16x8*)&buf[m * 264 + kt * 32 + quad * 8];
      bf16x8 b0 = *(const bf16x8*)&w2L[(ctg0 * 8 + kt) * 512 + lane * 8];
      bf16x8 b1r = *(const bf16x8*)&w2L[(ctg1 * 8 + kt) * 512 + lane * 8];
      c0 = __builtin_amdgcn_mfma_f32_16x16x32_bf16(zf, b0, c0, 0, 0, 0);
      c1 = __builtin_amdgcn_mfma_f32_16x16x32_bf16(zf, b1r, c1, 0, 0, 0);
    }
    int rb = t * 16 + quad * 4;
#pragma unroll
    for (int reg = 0; reg < 4; ++reg) {
      float o0 = c0[reg] + bv2[0];
      float o1 = c1[reg] + bv2[1];
      out[(size_t)(rb + reg) * HID + col0 + m] = f2bf(o0);
      out[(size_t)(rb + reg) * HID + col0 + 16 + m] = f2bf(o1);
      csum[0] += o0; csq[0] = fmaf(o0, o0, csq[0]);
      csum[1] += o1; csq[1] = fmaf(o1, o1, csq[1]);
    }
#pragma unroll
    for (int kt = 0; kt < 8; ++kt) af[kt] = afn[kt];
    parity ^= 1;
  }
#pragma unroll
  for (int ct = 0; ct < 2; ++ct) {
    float s = csum[ct], q = csq[ct];
    s += __shfl_xor(s, 16); s += __shfl_xor(s, 32);
    q += __shfl_xor(q, 16); q += __shfl_xor(q, 32);
    if (quad == 0) {
      unsafeAtomicAdd(&stats[col0 + ct * 16 + m], s);
      unsafeAtomicAdd(&stats[HID + col0 + ct * 16 + m], q);
    }
  }
}

// h(bf16) = relu(z*scale + shift) + h ; scale/shift computed from raw stats
__global__ __launch_bounds__(256) void k_bn_apply(const ushort_t* __restrict__ z,
    const float* __restrict__ stats, const float* __restrict__ g,
    const float* __restrict__ b, ushort_t* __restrict__ h, int total4)
{
  int idx = blockIdx.x * 256 + threadIdx.x;
  if (idx >= total4) return;
  int col = (idx & 63) * 4;
  const float inv_n = 1.f / (float)N_NODES;
  float sc[4], sh[4];
#pragma unroll
  for (int c = 0; c < 4; ++c) {
    float mu = stats[col + c] * inv_n;
    float var = stats[HID + col + c] * inv_n - mu * mu;
    float rs = rsqrtf(var + 1e-5f);
    sc[c] = g[col + c] * rs;
    sh[c] = b[col + c] - mu * sc[c];
  }
  ushort4 zv = *(const ushort4*)(z + (size_t)idx * 4);
  ushort4 hv = *(const ushort4*)(h + (size_t)idx * 4);
  float o0 = fmaxf(fmaf(bf2f(zv.x), sc[0], sh[0]), 0.f) + bf2f(hv.x);
  float o1 = fmaxf(fmaf(bf2f(zv.y), sc[1], sh[1]), 0.f) + bf2f(hv.y);
  float o2 = fmaxf(fmaf(bf2f(zv.z), sc[2], sh[2]), 0.f) + bf2f(hv.z);
  float o3 = fmaxf(fmaf(bf2f(zv.w), sc[3], sh[3]), 0.f) + bf2f(hv.w);
  *(ushort4*)(h + (size_t)idx * 4) = make_ushort4(f2bf(o0), f2bf(o1), f2bf(o2), f2bf(o3));
}

__device__ __forceinline__ int lbound(const int* __restrict__ b, int n, int key) {
  int lo = 0, hi = n;
  while (lo < hi) {
    int mid = (lo + hi) >> 1;
    if (b[mid] < key) lo = mid + 1; else hi = mid;
  }
  return lo;
}

// fused last-layer BN + pool: h_new = relu(z2*sc+sh) + h_old computed on
// the fly (h never written for the last layer — it's only read here).
// gf[g] = [mean | sum | max] as bf16.
__global__ __launch_bounds__(256) void k_pool_bn(const ushort_t* __restrict__ z,
    const float* __restrict__ stats, const float* __restrict__ g_,
    const float* __restrict__ b_, const ushort_t* __restrict__ h,
    const int* __restrict__ batch, ushort_t* __restrict__ gf)
{
  int g = blockIdx.x, j = threadIdx.x;
  const float inv_n = 1.f / (float)N_NODES;
  float mu = stats[j] * inv_n;
  float var = stats[HID + j] * inv_n - mu * mu;
  float rs = rsqrtf(var + 1e-5f);
  float sc = g_[j] * rs;
  float sh = b_[j] - mu * sc;
  int lo = lbound(batch, N_NODES, g);
  int hi = lbound(batch, N_NODES, g + 1);
  float s = 0.f, mx = 0.f;  // h >= 0 by construction
  for (int i = lo; i < hi; ++i) {
    float zv = bf2f(z[(size_t)i * HID + j]);
    float hv = bf2f(h[(size_t)i * HID + j]);
    float v = fmaxf(fmaf(zv, sc, sh), 0.f) + hv;
    s += v; mx = fmaxf(mx, v);
  }
  float cntv = fmaxf((float)(hi - lo), 1.f);
  size_t base = (size_t)g * 768;
  gf[base + j] = f2bf(s / cntv);
  gf[base + 256 + j] = f2bf(s);
  gf[base + 512 + j] = f2bf(mx);
}

// small B-in-registers MFMA GEMM for the head: out[M,N] = A[M,K] @ Bt^T + bias
template<int KT, int DO_RELU>
__global__ __launch_bounds__(256, 1) void k_head_gemm(const ushort_t* __restrict__ A,
    const ushort_t* __restrict__ Bt, const float* __restrict__ bias,
    ushort_t* __restrict__ out, int M, int N)
{
  const int K = KT * 32;
  int tid = threadIdx.x;
  int wave = tid >> 6, lane = tid & 63;
  int m = lane & 15, quad = lane >> 4;
  int col = (blockIdx.y * 4 + wave) * 16 + m;
  bf16x8 bfrag[KT];
#pragma unroll
  for (int kt = 0; kt < KT; ++kt)
    bfrag[kt] = *(const bf16x8*)(Bt + (size_t)col * K + kt * 32 + quad * 8);
  float bv = bias[col];
  int ntiles = M >> 4;
  for (int t = blockIdx.x; t < ntiles; t += gridDim.x) {
    const ushort_t* Ap = A + (size_t)(t * 16 + m) * K + quad * 8;
    bf16x8 af[KT];
#pragma unroll
    for (int kt = 0; kt < KT; ++kt) af[kt] = *(const bf16x8*)(Ap + kt * 32);
    f32x4 acc = (f32x4){0.f, 0.f, 0.f, 0.f};
#pragma unroll
    for (int kt = 0; kt < KT; ++kt)
      acc = __builtin_amdgcn_mfma_f32_16x16x32_bf16(af[kt], bfrag[kt], acc, 0, 0, 0);
    int rb = t * 16 + quad * 4;
#pragma unroll
    for (int reg = 0; reg < 4; ++reg) {
      float o = acc[reg] + bv;
      if (DO_RELU) o = fmaxf(o, 0.f);
      out[(size_t)(rb + reg) * N + col] = f2bf(o);
    }
  }
}

// out[g] = dot(g2[g], W3) + b3; one wave per graph
__global__ __launch_bounds__(256) void k_head_out(const ushort_t* __restrict__ g2,
    const float* __restrict__ W3, const float* __restrict__ b3,
    float* __restrict__ out)
{
  int wave = threadIdx.x >> 6, lane = threadIdx.x & 63;
  int g = blockIdx.x * 4 + wave;
  ushort2 v = *(const ushort2*)&g2[(size_t)g * 128 + lane * 2];
  float p = bf2f(v.x) * W3[lane * 2] + bf2f(v.y) * W3[lane * 2 + 1];
#pragma unroll
  for (int off = 32; off > 0; off >>= 1) p += __shfl_down(p, off);
  if (lane == 0) out[g] = p + b3[0];
}

extern "C" void kernel_launch(void* const* d_in, const int* in_sizes, int n_in,
                              void* d_out, int out_size, void* d_ws, size_t ws_size,
                              hipStream_t stream)
{
  const float* x     = (const float*)d_in[0];
  const int*   ei    = (const int*)d_in[1];
  const float* ea    = (const float*)d_in[2];
  const int*   batch = (const int*)d_in[3];
  const float* encW  = (const float*)d_in[4];
  const float* encB  = (const float*)d_in[5];
  const float* edgeW = (const float*)d_in[6];
  const float* edgeB = (const float*)d_in[7];
  const float* W1    = (const float*)d_in[8];
  const float* b1    = (const float*)d_in[9];
  const float* W2    = (const float*)d_in[10];
  const float* b2    = (const float*)d_in[11];
  const float* bng   = (const float*)d_in[12];
  const float* bnb   = (const float*)d_in[13];
  const float* hW1   = (const float*)d_in[14];
  const float* hb1   = (const float*)d_in[15];
  const float* hW2   = (const float*)d_in[16];
  const float* hb2   = (const float*)d_in[17];
  const float* hW3   = (const float*)d_in[18];
  const float* hb3   = (const float*)d_in[19];
  float* out = (float*)d_out;

  const size_t NH = (size_t)N_NODES * HID;
  char* base = (char*)d_ws;
  auto alloc = [&](size_t bytes) -> char* {
    char* p = base; base += (bytes + 63) & ~(size_t)63; return p;
  };
  float*    stats = (float*)alloc(512 * 4);
  int*      offs  = (int*)alloc(50001 * 4);
  int*      btot  = (int*)alloc(64 * 4);
  int*      esrc  = (int*)alloc((size_t)N_EDGES * 4);
  ushort_t* eab   = (ushort_t*)alloc((size_t)N_EDGES * 8 * 2);
  ushort_t* Wt1   = (ushort_t*)alloc((size_t)NLAYERS * HID * HID * 2);
  ushort_t* Wt2   = (ushort_t*)alloc((size_t)NLAYERS * HID * HID * 2);
  ushort_t* hW1t  = (ushort_t*)alloc((size_t)768 * 256 * 2);
  ushort_t* hW2t  = (ushort_t*)alloc((size_t)256 * 128 * 2);
  ushort_t* gf    = (ushort_t*)alloc((size_t)G_GRAPHS * 768 * 2);
  ushort_t* g1    = (ushort_t*)alloc((size_t)G_GRAPHS * 256 * 2);
  ushort_t* g2    = (ushort_t*)alloc((size_t)G_GRAPHS * 128 * 2);
  ushort_t* zin   = (ushort_t*)alloc(NH * 2);  // also reused as z2
  ushort_t* h     = (ushort_t*)alloc(NH * 2);
  // total ~84 MB

  const int* src = ei;
  const int* dst = ei + N_EDGES;

  // setup: CSR build + weight prep (once per call)
  hipMemsetAsync(offs, 0, 50001 * sizeof(int), stream);
  k_hist<<<(N_EDGES + 255) / 256, 256, 0, stream>>>(dst, offs, N_EDGES);
  const int NSB = (N_NODES + 1023) / 1024;  // 49
  k_scanA<<<NSB, 1024, 0, stream>>>(offs, btot, N_NODES);
  k_scanC<<<NSB, 1024, 0, stream>>>(offs, btot, N_NODES);
  k_fill<<<(N_EDGES + 255) / 256, 256, 0, stream>>>(src, dst, offs, esrc, eab, ea, N_EDGES);
  k_prep<<<dim3(16, 2 * NLAYERS), 256, 0, stream>>>(W1, W2, Wt1, Wt2);
  k_prept<<<(768 * 256 + 255) / 256, 256, 0, stream>>>(hW1, hW1t, 768, 256);
  k_prept<<<(256 * 128 + 255) / 256, 256, 0, stream>>>(hW2, hW2t, 256, 128);

  k_encoder<<<(N_NODES + 7) / 8, 256, 0, stream>>>(x, encW, encB, h, N_NODES);

  for (int l = 0; l < NLAYERS; ++l) {
    k_gather<<<N_NODES / 4, 256, 0, stream>>>(
        h, offs, esrc, eab, edgeW + (size_t)l * 5 * HID, edgeB + (size_t)l * HID,
        zin, stats, N_NODES);
    k_mlp<<<256, 512, 0, stream>>>(
        zin, Wt1 + (size_t)l * HID * HID, b1 + (size_t)l * HID,
        Wt2 + (size_t)l * HID * HID, b2 + (size_t)l * HID, zin, stats, N_NODES);
    if (l < NLAYERS - 1) {
      k_bn_apply<<<(N_NODES * HID / 4 + 255) / 256, 256, 0, stream>>>(
          zin, stats, bng + (size_t)l * HID, bnb + (size_t)l * HID, h,
          N_NODES * HID / 4);
    }
  }

  // last layer: BN fused into pool (h only read, never re-written)
  k_pool_bn<<<G_GRAPHS, 256, 0, stream>>>(
      zin, stats, bng + (size_t)(NLAYERS - 1) * HID,
      bnb + (size_t)(NLAYERS - 1) * HID, h, batch, gf);
  k_head_gemm<24, 1><<<dim3(16, 4), 256, 0, stream>>>(gf, hW1t, hb1, g1, G_GRAPHS, 256);
  k_head_gemm<8, 1><<<dim3(16, 2), 256, 0, stream>>>(g1, hW2t, hb2, g2, G_GRAPHS, 128);
  k_head_out<<<G_GRAPHS / 4, 256, 0, stream>>>(g2, hW3, hb3, out);
}